// Round 5
// baseline (584.901 us; speedup 1.0000x reference)
//
#include <hip/hip_runtime.h>

// ---------------- problem constants ----------------
#define NUM_GRAPHS 64
#define NODE_SZ    200
#define FEAT       200
#define HID        256
#define HALF       128
#define N_NODES    (NUM_GRAPHS * NODE_SZ)   // 12800
#define KREAD      (NODE_SZ * HID)          // 51200

typedef unsigned short ushort_t;
typedef unsigned int uint_t;
typedef __attribute__((ext_vector_type(8))) short bf16x8;
typedef __attribute__((ext_vector_type(4))) float f32x4;

#define GAS(p) ((const __attribute__((address_space(1))) void*)(p))
#define LAS(p) ((__attribute__((address_space(3))) void*)(p))

__device__ __forceinline__ float bf2f(ushort_t u) {
    union { unsigned int i; float f; } v; v.i = ((unsigned int)u) << 16; return v.f;
}
__device__ __forceinline__ ushort_t f2bf(float f) {
    union { float f; unsigned int i; } v; v.f = f;
    unsigned int x = v.i;
    unsigned int r = (x + 0x7fffu + ((x >> 16) & 1u)) >> 16;  // RNE
    return (ushort_t)r;
}

// ---------------- workspace offsets (bytes) ----------------
#define OFF_CNT    0              // 12800 u32 = 51,200
#define OFF_DONE   51200          // 16 u32
#define OFF_WEFF   51264          // 51200 f32 = 204,800
#define OFF_OBND   256064         // 12801 uint2 = 102,408
#define OFF_RANK   358472         // 409600 u16 = 819,200
#define OFF_ES     1177672        // 409600 uint2 = 3,276,800
#define OFF_YALL   4454480        // 12800*512*2 = 13,107,200
#define OFF_HA     17561680       // 6,553,600
#define OFF_HB     24115280       // 6,553,600
#define OFF_WALL   30668880       // 3*512*256*2 = 786,432
#define OFF_XB     31455312       // 6,553,600 -> 38,008,912

// ---------------- K1: casts + weff + histogram(+ranks) + last-block scan ----------------
// blocks [0,50): xb cast | [50,98): wall cast | [98,148): weff | [148,..): hist.
// Weight layout per layer (wall, [512 x 256] bf16):
//   rows 0..127: Wp[:, :K] | 128..255: Wn[:, :K] | 256..383: Wp[:, K:] | 384..511: Wn[:, K:]
__global__ __launch_bounds__(1024) void k1_kernel(
        const float* __restrict__ Wp0, const float* __restrict__ Wn0,
        const float* __restrict__ Wp1, const float* __restrict__ Wn1,
        const float* __restrict__ Wp2, const float* __restrict__ Wn2,
        const float* __restrict__ x, const float* __restrict__ Wr,
        const float* __restrict__ Wl,
        const int* __restrict__ ei, const float* __restrict__ ew, int E,
        uint_t* __restrict__ cnt, ushort_t* __restrict__ rank16,
        ushort_t* __restrict__ wall, ushort_t* __restrict__ xb,
        float* __restrict__ weff, uint_t* __restrict__ done,
        uint2* __restrict__ obnd, int nblk) {
    int bx = blockIdx.x, tid = threadIdx.x;
    if (bx < 50) {                                  // ---- xb cast/pad ----
        for (int idx = bx * 1024 + tid; idx < N_NODES * 64; idx += 51200) {
            int n = idx >> 6, c0 = (idx & 63) * 4;
            ushort4 o = {0, 0, 0, 0};
            if (c0 < 200) {
                float4 v = *(const float4*)&x[(size_t)n * 200 + c0];
                o.x = f2bf(v.x); o.y = f2bf(v.y); o.z = f2bf(v.z); o.w = f2bf(v.w);
            }
            *(ushort4*)&xb[(size_t)n * 256 + c0] = o;
        }
    } else if (bx < 98) {                           // ---- wall rearrange/cast ----
        for (int idx = (bx - 50) * 1024 + tid; idx < 3 * 131072; idx += 49152) {
            int layer = idx >> 17, within = idx & 131071;
            int rr = within >> 8, col = within & 255;
            const float* Wp = (layer == 0) ? Wp0 : (layer == 1) ? Wp1 : Wp2;
            const float* Wn = (layer == 0) ? Wn0 : (layer == 1) ? Wn1 : Wn2;
            int Ks = (layer == 0) ? 200 : 256;
            int q = rr >> 7;                        // 0:Pl 1:Nl 2:Pr 3:Nr
            const float* Wsrc = (q & 1) ? Wn : Wp;
            int row = rr & 127;
            int scol = col + ((q >> 1) ? Ks : 0);
            float v = (col < Ks) ? Wsrc[(size_t)row * (2 * Ks) + scol] : 0.0f;
            wall[idx] = f2bf(v);
        }
    } else if (bx < 148) {                          // ---- weff[k] = sum_c Wl[c]*Wr[c,k] ----
        int k = (bx - 98) * 1024 + tid;             // < 51200
        float s0 = 0.f, s1 = 0.f, s2 = 0.f, s3 = 0.f;
#pragma unroll 1
        for (int c = 0; c < 256; c += 4) {
            s0 = fmaf(Wl[c + 0], Wr[(size_t)(c + 0) * KREAD + k], s0);
            s1 = fmaf(Wl[c + 1], Wr[(size_t)(c + 1) * KREAD + k], s1);
            s2 = fmaf(Wl[c + 2], Wr[(size_t)(c + 2) * KREAD + k], s2);
            s3 = fmaf(Wl[c + 3], Wr[(size_t)(c + 3) * KREAD + k], s3);
        }
        weff[k] = (s0 + s1) + (s2 + s3);
    } else {                                        // ---- histogram + rank record ----
        int e = (bx - 148) * 1024 + tid;
        if (e < E) {
            int dst = ei[E + e];
            float w = ew[e];
            if (w > 0.0f) {
                uint_t old = atomicAdd(&cnt[dst], 1u);
                rank16[e] = (ushort_t)(old & 0xffffu);
            } else if (w < 0.0f) {
                uint_t old = atomicAdd(&cnt[dst], 0x10000u);
                rank16[e] = (ushort_t)(old >> 16);
            }
        }
    }

    // ---- done-count; last block runs the exclusive scan -> obnd ----
    __syncthreads();
    __threadfence();
    __shared__ uint_t lastFlag;
    if (tid == 0)
        lastFlag = (atomicAdd(done, 1u) == (uint_t)(nblk - 1)) ? 1u : 0u;
    __syncthreads();
    if (lastFlag) {
        __threadfence();
        const int PER = 13;
        int t = tid;
        int start = t * PER;
        int local[PER];
        uint_t pcnt[PER];
        int sum = 0;
#pragma unroll
        for (int i = 0; i < PER; ++i) {
            int idx = start + i;
            uint_t c = (idx < N_NODES) ? cnt[idx] : 0u;
            int v = (int)((c & 0xffffu) + (c >> 16));
            pcnt[i] = c & 0xffffu;
            local[i] = sum;
            sum += v;
        }
        int lane = t & 63, wid = t >> 6;
        int inc = sum;
#pragma unroll
        for (int d = 1; d < 64; d <<= 1) {
            int up = __shfl_up(inc, d);
            if (lane >= d) inc += up;
        }
        __shared__ int wsum[16], woff[16];
        if (lane == 63) wsum[wid] = inc;
        __syncthreads();
        if (t < 16) {
            int acc = 0;
            for (int j = 0; j < 16; ++j) if (j < t) acc += wsum[j];
            woff[t] = acc;
        }
        __syncthreads();
        int base = woff[wid] + (inc - sum);
#pragma unroll
        for (int i = 0; i < PER; ++i) {
            int idx = start + i;
            if (idx < N_NODES) {
                uint_t off = (uint_t)(base + local[i]);
                obnd[idx] = make_uint2(off, off + pcnt[i]);
            }
        }
        if (t == 1023) {
            uint_t tot = (uint_t)(base + sum);
            obnd[N_NODES] = make_uint2(tot, tot);
        }
    }
}

// ---------------- GEMM body: Y = A @ W^T, tile 128M x 256N, 8 waves, BK=32 ----------------
__device__ __forceinline__ void gemm_body(int t, const ushort_t* __restrict__ A,
                                          const ushort_t* __restrict__ Bw,
                                          ushort_t* __restrict__ Y,
                                          ushort_t* smem) {
    int mBase = (t >> 1) * 128;
    int nBase = (t & 1) * 256;
    int tid  = threadIdx.x;
    int lane = tid & 63;
    int wv   = tid >> 6;
    int r    = lane & 15;
    int quad = lane >> 4;
    int wm   = wv >> 1;        // 0..3 : M 32-block
    int wn   = wv & 1;         // 0..1 : N 128-block

    int rowA = tid >> 2, colc = (tid & 3) * 8;
    const ushort_t* gA  = A  + (size_t)(mBase + rowA) * 256 + colc;
    const ushort_t* gB0 = Bw + (size_t)(nBase + rowA) * 256 + colc;
    const ushort_t* gB1 = Bw + (size_t)(nBase + 128 + rowA) * 256 + colc;

    f32x4 acc[2][8];
#pragma unroll
    for (int i = 0; i < 2; ++i)
#pragma unroll
        for (int j = 0; j < 8; ++j) acc[i][j] = (f32x4){0.f, 0.f, 0.f, 0.f};

    auto STAGE = [&](int buf, int kb) {
        ushort_t* Ad = smem + (buf << 12) + tid * 8;
        ushort_t* Bd = smem + 8192 + (buf << 13) + tid * 8;
        __builtin_amdgcn_global_load_lds(GAS(gA + kb), LAS(Ad), 16, 0, 0);
        __builtin_amdgcn_global_load_lds(GAS(gB0 + kb), LAS(Bd), 16, 0, 0);
        __builtin_amdgcn_global_load_lds(GAS(gB1 + kb), LAS(Bd + 4096), 16, 0, 0);
    };

    STAGE(0, 0);
    for (int kt = 0; kt < 8; ++kt) {
        int cb = kt & 1;
        __syncthreads();
        if (kt < 7) STAGE(cb ^ 1, (kt + 1) * 32);
        const ushort_t* Ac = smem + (cb << 12);
        const ushort_t* Bc = smem + 8192 + (cb << 13);
        bf16x8 af[2];
#pragma unroll
        for (int i = 0; i < 2; ++i)
            af[i] = *(const bf16x8*)&Ac[(wm * 32 + i * 16 + r) * 32 + quad * 8];
#pragma unroll
        for (int j = 0; j < 8; ++j) {
            bf16x8 bfr = *(const bf16x8*)&Bc[(wn * 128 + j * 16 + r) * 32 + quad * 8];
            acc[0][j] = __builtin_amdgcn_mfma_f32_16x16x32_bf16(af[0], bfr, acc[0][j], 0, 0, 0);
            acc[1][j] = __builtin_amdgcn_mfma_f32_16x16x32_bf16(af[1], bfr, acc[1][j], 0, 0, 0);
        }
    }
#pragma unroll
    for (int i = 0; i < 2; ++i)
#pragma unroll
        for (int j = 0; j < 8; ++j) {
            int c = nBase + wn * 128 + j * 16 + r;
#pragma unroll
            for (int reg = 0; reg < 4; ++reg) {
                int m = mBase + wm * 32 + i * 16 + quad * 4 + reg;
                Y[(size_t)m * 512 + c] = f2bf(acc[i][j][reg]);
            }
        }
}

// ---------------- K3: scatter (via precomputed ranks) + GEMM layer 0 ----------------
__global__ __launch_bounds__(512) void scatgemm_kernel(
        const int* __restrict__ ei, const float* __restrict__ ew,
        const uint2* __restrict__ obnd, const ushort_t* __restrict__ rank16,
        uint2* __restrict__ es, int E,
        const ushort_t* __restrict__ xb, const ushort_t* __restrict__ wall,
        ushort_t* __restrict__ Yall) {
    __shared__ __align__(16) ushort_t smem[24576];
    int bx = blockIdx.x;
    if (bx < 200) {
        gemm_body(bx, xb, wall, Yall, smem);
        return;
    }
    int e = (bx - 200) * 512 + threadIdx.x;
    if (e < E) {
        int src = ei[e];
        int dst = ei[E + e];
        float w = ew[e];
        uint_t rk = rank16[e];
        if (w > 0.0f)
            es[obnd[dst].x + rk] = make_uint2((uint_t)src, __float_as_uint(w));
        else if (w < 0.0f)
            es[obnd[dst].y + rk] = make_uint2((uint_t)src, __float_as_uint(-w));
    }
}

// ---------------- standalone GEMM kernel (layers 1,2) ----------------
__global__ __launch_bounds__(512) void gemm_kernel(const ushort_t* __restrict__ A,
                                                   const ushort_t* __restrict__ Bw,
                                                   ushort_t* __restrict__ Y) {
    __shared__ __align__(16) ushort_t smem[24576];
    gemm_body(blockIdx.x, A, Bw, Y, smem);
}

// ---------------- aggregate projected rows + combine; DOT variant fuses readout ----------------
template <bool LEAKY, bool DOT>
__global__ __launch_bounds__(256) void agg_kernel(
        const ushort_t* __restrict__ Y,      // [12800 x 512]: Yp | Yn | Zp | Zn
        const uint2* __restrict__ obnd,
        const uint2* __restrict__ es,
        const float* __restrict__ bp, const float* __restrict__ bn,
        ushort_t* __restrict__ outp,         // !DOT: [12800 x 256]
        const float* __restrict__ weff,      // DOT: [51200]
        float* __restrict__ outg,            // DOT: [64] (pre-zeroed)
        const float* __restrict__ br, const float* __restrict__ Wl,
        const float* __restrict__ bl) {
    int lane = threadIdx.x & 63;
    int wv   = threadIdx.x >> 6;
    int n = blockIdx.x * 4 + wv;
    int c0 = lane * 2;                       // 2 cols per lane, 0..127

    if (DOT && blockIdx.x < NUM_GRAPHS && wv == 0) {   // bias: br.Wl + bl, once per graph
        float p = br[lane] * Wl[lane] + br[lane + 64] * Wl[lane + 64]
                + br[lane + 128] * Wl[lane + 128] + br[lane + 192] * Wl[lane + 192];
#pragma unroll
        for (int d = 32; d > 0; d >>= 1) p += __shfl_xor(p, d);
        if (lane == 0) atomicAdd(&outg[blockIdx.x], p + bl[0]);
    }

    uint2 ob = obnd[n];
    uint_t off = ob.x, mid = ob.y, end = obnd[n + 1].x;

    float accp[2] = {0.f, 0.f};
    float accn[2] = {0.f, 0.f};

#pragma unroll 1
    for (int phase = 0; phase < 2; ++phase) {
        uint_t lo = phase ? mid : off;
        uint_t hi = phase ? end : mid;
        float* acc = phase ? accn : accp;
        const ushort_t* Yb = Y + (phase ? 128 : 0) + c0;
#pragma unroll 1
        for (uint_t base = lo; base < hi; base += 64) {
            int cnt = (int)min(64u, hi - base);
            uint2 rec = es[base + (uint_t)min(lane, cnt - 1)];
            int i = 0;
#pragma unroll 1
            for (; i + 8 <= cnt; i += 8) {
                int s[8]; float w[8]; uint_t u[8];
#pragma unroll
                for (int j = 0; j < 8; ++j) {
                    s[j] = __shfl((int)rec.x, i + j);
                    w[j] = __uint_as_float((uint_t)__shfl((int)rec.y, i + j));
                }
#pragma unroll
                for (int j = 0; j < 8; ++j) u[j] = *(const uint_t*)&Yb[(size_t)s[j] * 512];
#pragma unroll
                for (int j = 0; j < 8; ++j) {
                    acc[0] = fmaf(w[j], bf2f((ushort_t)(u[j] & 0xffffu)), acc[0]);
                    acc[1] = fmaf(w[j], bf2f((ushort_t)(u[j] >> 16)), acc[1]);
                }
            }
#pragma unroll 1
            for (; i < cnt; ++i) {
                int s = __shfl((int)rec.x, i);
                float w = __uint_as_float((uint_t)__shfl((int)rec.y, i));
                uint_t u = *(const uint_t*)&Yb[(size_t)s * 512];
                acc[0] = fmaf(w, bf2f((ushort_t)(u & 0xffffu)), acc[0]);
                acc[1] = fmaf(w, bf2f((ushort_t)(u >> 16)), acc[1]);
            }
        }
    }

    float dp = fmaxf((float)(mid - off), 1.0f);
    float dn = fmaxf((float)(end - mid), 1.0f);
    float rp = 1.0f / dp, rn = 1.0f / dn;
    uint_t zp = *(const uint_t*)&Y[(size_t)n * 512 + 256 + c0];
    uint_t zn = *(const uint_t*)&Y[(size_t)n * 512 + 384 + c0];
    float vp0 = fmaf(accp[0], rp, bf2f((ushort_t)(zp & 0xffffu)) + bp[c0]);
    float vp1 = fmaf(accp[1], rp, bf2f((ushort_t)(zp >> 16))     + bp[c0 + 1]);
    float vn0 = fmaf(accn[0], rn, bf2f((ushort_t)(zn & 0xffffu)) + bn[c0]);
    float vn1 = fmaf(accn[1], rn, bf2f((ushort_t)(zn >> 16))     + bn[c0 + 1]);
    if (LEAKY) {
        vp0 = (vp0 > 0.0f) ? vp0 : 0.01f * vp0;
        vp1 = (vp1 > 0.0f) ? vp1 : 0.01f * vp1;
        vn0 = (vn0 > 0.0f) ? vn0 : 0.01f * vn0;
        vn1 = (vn1 > 0.0f) ? vn1 : 0.01f * vn1;
    }
    if (DOT) {
        int g = n / 200;
        int kbase = (n - g * 200) * 256;
        float s = vp0 * weff[kbase + c0] + vp1 * weff[kbase + c0 + 1]
                + vn0 * weff[kbase + 128 + c0] + vn1 * weff[kbase + 128 + c0 + 1];
#pragma unroll
        for (int d = 32; d > 0; d >>= 1) s += __shfl_xor(s, d);
        if (lane == 0) atomicAdd(&outg[g], s);
    } else {
        uint_t op = (uint_t)f2bf(vp0) | ((uint_t)f2bf(vp1) << 16);
        uint_t on = (uint_t)f2bf(vn0) | ((uint_t)f2bf(vn1) << 16);
        *(uint_t*)&outp[(size_t)n * 256 + c0]       = op;
        *(uint_t*)&outp[(size_t)n * 256 + 128 + c0] = on;
    }
}

// ---------------- launch ----------------
extern "C" void kernel_launch(void* const* d_in, const int* in_sizes, int n_in,
                              void* d_out, int out_size, void* d_ws, size_t ws_size,
                              hipStream_t stream) {
    const float* x  = (const float*)d_in[0];
    const int*   ei = (const int*)d_in[1];
    const float* ew = (const float*)d_in[2];
    const float* Wp0 = (const float*)d_in[4];
    const float* bp0 = (const float*)d_in[5];
    const float* Wn0 = (const float*)d_in[6];
    const float* bn0 = (const float*)d_in[7];
    const float* Wp1 = (const float*)d_in[8];
    const float* bp1 = (const float*)d_in[9];
    const float* Wn1 = (const float*)d_in[10];
    const float* bn1 = (const float*)d_in[11];
    const float* Wp2 = (const float*)d_in[12];
    const float* bp2 = (const float*)d_in[13];
    const float* Wn2 = (const float*)d_in[14];
    const float* bn2 = (const float*)d_in[15];
    const float* Wr  = (const float*)d_in[16];
    const float* br  = (const float*)d_in[17];
    const float* Wl  = (const float*)d_in[18];
    const float* bl  = (const float*)d_in[19];
    const int E = in_sizes[1] / 2;   // 409600

    char* ws = (char*)d_ws;
    uint_t*   cnt    = (uint_t*)(ws + OFF_CNT);
    uint_t*   done   = (uint_t*)(ws + OFF_DONE);
    float*    weff   = (float*)(ws + OFF_WEFF);
    uint2*    obnd   = (uint2*)(ws + OFF_OBND);
    ushort_t* rank16 = (ushort_t*)(ws + OFF_RANK);
    uint2*    es     = (uint2*)(ws + OFF_ES);
    ushort_t* Yall   = (ushort_t*)(ws + OFF_YALL);
    ushort_t* hA     = (ushort_t*)(ws + OFF_HA);
    ushort_t* hB     = (ushort_t*)(ws + OFF_HB);
    ushort_t* wall   = (ushort_t*)(ws + OFF_WALL);
    ushort_t* xb     = (ushort_t*)(ws + OFF_XB);
    float*    outg   = (float*)d_out;

    // zero cnt+done (contiguous) and the output accumulator
    hipMemsetAsync(ws + OFF_CNT, 0, 51200 + 64, stream);
    hipMemsetAsync(d_out, 0, out_size, stream);

    // K1: casts + weff + histogram(+ranks) + last-block scan
    int histBlocks = (E + 1023) / 1024;
    int k1Grid = 148 + histBlocks;
    hipLaunchKernelGGL(k1_kernel, dim3(k1Grid), dim3(1024), 0, stream,
                       Wp0, Wn0, Wp1, Wn1, Wp2, Wn2, x, Wr, Wl,
                       ei, ew, E, cnt, rank16, wall, xb, weff, done, obnd, k1Grid);
    // K3: scatter + GEMM layer 0
    hipLaunchKernelGGL(scatgemm_kernel, dim3(200 + (E + 511) / 512), dim3(512), 0, stream,
                       ei, ew, obnd, rank16, es, E, xb, wall, Yall);
    // layer 0 agg
    hipLaunchKernelGGL((agg_kernel<true, false>), dim3(N_NODES / 4), dim3(256), 0, stream,
                       Yall, obnd, es, bp0, bn0, hA, (const float*)nullptr,
                       (float*)nullptr, (const float*)nullptr, (const float*)nullptr,
                       (const float*)nullptr);
    // layer 1
    hipLaunchKernelGGL(gemm_kernel, dim3(200), dim3(512), 0, stream, hA, wall + 131072, Yall);
    hipLaunchKernelGGL((agg_kernel<true, false>), dim3(N_NODES / 4), dim3(256), 0, stream,
                       Yall, obnd, es, bp1, bn1, hB, (const float*)nullptr,
                       (float*)nullptr, (const float*)nullptr, (const float*)nullptr,
                       (const float*)nullptr);
    // layer 2
    hipLaunchKernelGGL(gemm_kernel, dim3(200), dim3(512), 0, stream, hB, wall + 262144, Yall);
    // agg2 + fused readout dot
    hipLaunchKernelGGL((agg_kernel<false, true>), dim3(N_NODES / 4), dim3(256), 0, stream,
                       Yall, obnd, es, bp2, bn2, (ushort_t*)nullptr, weff,
                       outg, br, Wl, bl);
}

// Round 6
// 357.704 us; speedup vs baseline: 1.6352x; 1.6352x over previous
//
#include <hip/hip_runtime.h>

// ---------------- problem constants ----------------
#define NUM_GRAPHS 64
#define NODE_SZ    200
#define FEAT       200
#define HID        256
#define HALF       128
#define N_NODES    (NUM_GRAPHS * NODE_SZ)   // 12800
#define KREAD      (NODE_SZ * HID)          // 51200

typedef unsigned short ushort_t;
typedef unsigned int uint_t;
typedef __attribute__((ext_vector_type(8))) short bf16x8;
typedef __attribute__((ext_vector_type(4))) float f32x4;

#define GAS(p) ((const __attribute__((address_space(1))) void*)(p))
#define LAS(p) ((__attribute__((address_space(3))) void*)(p))

__device__ __forceinline__ float bf2f(ushort_t u) {
    union { unsigned int i; float f; } v; v.i = ((unsigned int)u) << 16; return v.f;
}
__device__ __forceinline__ ushort_t f2bf(float f) {
    union { float f; unsigned int i; } v; v.f = f;
    unsigned int x = v.i;
    unsigned int r = (x + 0x7fffu + ((x >> 16) & 1u)) >> 16;  // RNE
    return (ushort_t)r;
}

// ---------------- workspace offsets (bytes) ----------------
#define OFF_CNT    0              // 12800 u32 = 51,200
#define OFF_WEFF   51264          // 51200 f32 = 204,800
#define OFF_OBND   256064         // 12801 uint2 = 102,408
#define OFF_RANK   358472         // 409600 u16 = 819,200
#define OFF_ES     1177672        // 409600 uint2 = 3,276,800
#define OFF_YALL   4454480        // 12800*512*2 = 13,107,200
#define OFF_HA     17561680       // 6,553,600
#define OFF_HB     24115280       // 6,553,600
#define OFF_WALL   30668880       // 3*512*256*2 = 786,432
#define OFF_XB     31455312       // 6,553,600 -> 38,008,912

// ---------------- K1: zero cnt + wall cast + xb cast + weff ----------------
// Weight layout per layer (wall, [512 x 256] bf16):
//   rows 0..127: Wp[:, :K] | 128..255: Wn[:, :K] | 256..383: Wp[:, K:] | 384..511: Wn[:, K:]
// K=200 for layer 0 (cols 200..255 zero), K=256 for layers 1,2.
__global__ __launch_bounds__(256) void prep_kernel(
        const float* __restrict__ Wp0, const float* __restrict__ Wn0,
        const float* __restrict__ Wp1, const float* __restrict__ Wn1,
        const float* __restrict__ Wp2, const float* __restrict__ Wn2,
        const float* __restrict__ x, const float* __restrict__ Wr,
        const float* __restrict__ Wl,
        uint_t* __restrict__ cnt, ushort_t* __restrict__ wall,
        ushort_t* __restrict__ xb, float* __restrict__ weff) {
    int gid = blockIdx.x * 256 + threadIdx.x;
    const int GS = gridDim.x * 256;                  // 131072
    for (int i = gid; i < N_NODES; i += GS) cnt[i] = 0u;
    for (int idx = gid; idx < 3 * 131072; idx += GS) {
        int layer = idx >> 17, within = idx & 131071;
        int rr = within >> 8, col = within & 255;
        const float* Wp = (layer == 0) ? Wp0 : (layer == 1) ? Wp1 : Wp2;
        const float* Wn = (layer == 0) ? Wn0 : (layer == 1) ? Wn1 : Wn2;
        int Ks = (layer == 0) ? 200 : 256;
        int q = rr >> 7;                             // 0:Pl 1:Nl 2:Pr 3:Nr
        const float* Wsrc = (q & 1) ? Wn : Wp;
        int row = rr & 127;
        int scol = col + ((q >> 1) ? Ks : 0);
        float v = (col < Ks) ? Wsrc[(size_t)row * (2 * Ks) + scol] : 0.0f;
        wall[idx] = f2bf(v);
    }
    for (int idx = gid; idx < N_NODES * 64; idx += GS) {
        int n = idx >> 6, c0 = (idx & 63) * 4;
        ushort4 o = {0, 0, 0, 0};
        if (c0 < 200) {
            float4 v = *(const float4*)&x[(size_t)n * 200 + c0];
            o.x = f2bf(v.x); o.y = f2bf(v.y); o.z = f2bf(v.z); o.w = f2bf(v.w);
        }
        *(ushort4*)&xb[(size_t)n * 256 + c0] = o;
    }
    // weff[k] = sum_c Wl[c] * Wr[c, k]   (ILP-8 over c)
    for (int k = gid; k < KREAD; k += GS) {
        float s[8] = {0.f, 0.f, 0.f, 0.f, 0.f, 0.f, 0.f, 0.f};
#pragma unroll 1
        for (int c = 0; c < 256; c += 8) {
#pragma unroll
            for (int j = 0; j < 8; ++j)
                s[j] = fmaf(Wl[c + j], Wr[(size_t)(c + j) * KREAD + k], s[j]);
        }
        weff[k] = ((s[0] + s[1]) + (s[2] + s[3])) + ((s[4] + s[5]) + (s[6] + s[7]));
    }
}

// ---------------- K2: degree histogram + per-edge rank (atomic return) ----------------
__global__ __launch_bounds__(512) void hist_kernel(const int* __restrict__ ei,
                                                   const float* __restrict__ ew,
                                                   uint_t* __restrict__ cnt,
                                                   ushort_t* __restrict__ rank16, int E) {
    int e = blockIdx.x * 512 + threadIdx.x;
    if (e < E) {
        int dst = ei[E + e];
        float w = ew[e];
        if (w > 0.0f) {
            uint_t old = atomicAdd(&cnt[dst], 1u);
            rank16[e] = (ushort_t)(old & 0xffffu);
        } else if (w < 0.0f) {
            uint_t old = atomicAdd(&cnt[dst], 0x10000u);
            rank16[e] = (ushort_t)(old >> 16);
        }
    }
}

// ---------------- K3: exclusive scan over packed counts -> obnd; bias-init outg ----------------
__global__ __launch_bounds__(1024) void scan_kernel(const uint_t* __restrict__ cnt,
                                                    uint2* __restrict__ obnd,
                                                    const float* __restrict__ br,
                                                    const float* __restrict__ Wl,
                                                    const float* __restrict__ bl,
                                                    float* __restrict__ outg, int n) {
    const int PER = 13;
    int t = threadIdx.x;
    int start = t * PER;
    int local[PER];
    uint_t pcnt[PER];
    int sum = 0;
#pragma unroll
    for (int i = 0; i < PER; ++i) {
        int idx = start + i;
        uint_t c = (idx < n) ? cnt[idx] : 0u;
        int v = (int)((c & 0xffffu) + (c >> 16));
        pcnt[i] = c & 0xffffu;
        local[i] = sum;
        sum += v;
    }
    int lane = t & 63, wid = t >> 6;
    int inc = sum;
#pragma unroll
    for (int d = 1; d < 64; d <<= 1) {
        int up = __shfl_up(inc, d);
        if (lane >= d) inc += up;
    }
    __shared__ int wsum[16], woff[16];
    if (lane == 63) wsum[wid] = inc;
    __syncthreads();
    if (t < 16) {
        int acc = 0;
        for (int j = 0; j < 16; ++j) if (j < t) acc += wsum[j];
        woff[t] = acc;
    }
    __syncthreads();
    int base = woff[wid] + (inc - sum);
#pragma unroll
    for (int i = 0; i < PER; ++i) {
        int idx = start + i;
        if (idx < n) {
            uint_t off = (uint_t)(base + local[i]);
            obnd[idx] = make_uint2(off, off + pcnt[i]);
        }
    }
    if (t == 1023) {
        uint_t tot = (uint_t)(base + sum);
        obnd[n] = make_uint2(tot, tot);
    }
    // bias-init: outg[g] = sum_c br[c]*Wl[c] + bl  (wave 0; butterfly gives all lanes the sum)
    if (t < 64) {
        float p = br[t] * Wl[t] + br[t + 64] * Wl[t + 64]
                + br[t + 128] * Wl[t + 128] + br[t + 192] * Wl[t + 192];
#pragma unroll
        for (int d = 32; d > 0; d >>= 1) p += __shfl_xor(p, d);
        outg[t] = p + bl[0];
    }
}

// ---------------- GEMM body: Y = A @ W^T, tile 128M x 256N, 8 waves, BK=32 ----------------
__device__ __forceinline__ void gemm_body(int t, const ushort_t* __restrict__ A,
                                          const ushort_t* __restrict__ Bw,
                                          ushort_t* __restrict__ Y,
                                          ushort_t* smem) {
    int mBase = (t >> 1) * 128;
    int nBase = (t & 1) * 256;
    int tid  = threadIdx.x;
    int lane = tid & 63;
    int wv   = tid >> 6;
    int r    = lane & 15;
    int quad = lane >> 4;
    int wm   = wv >> 1;        // 0..3 : M 32-block
    int wn   = wv & 1;         // 0..1 : N 128-block

    int rowA = tid >> 2, colc = (tid & 3) * 8;
    const ushort_t* gA  = A  + (size_t)(mBase + rowA) * 256 + colc;
    const ushort_t* gB0 = Bw + (size_t)(nBase + rowA) * 256 + colc;
    const ushort_t* gB1 = Bw + (size_t)(nBase + 128 + rowA) * 256 + colc;

    f32x4 acc[2][8];
#pragma unroll
    for (int i = 0; i < 2; ++i)
#pragma unroll
        for (int j = 0; j < 8; ++j) acc[i][j] = (f32x4){0.f, 0.f, 0.f, 0.f};

    auto STAGE = [&](int buf, int kb) {
        ushort_t* Ad = smem + (buf << 12) + tid * 8;
        ushort_t* Bd = smem + 8192 + (buf << 13) + tid * 8;
        __builtin_amdgcn_global_load_lds(GAS(gA + kb), LAS(Ad), 16, 0, 0);
        __builtin_amdgcn_global_load_lds(GAS(gB0 + kb), LAS(Bd), 16, 0, 0);
        __builtin_amdgcn_global_load_lds(GAS(gB1 + kb), LAS(Bd + 4096), 16, 0, 0);
    };

    STAGE(0, 0);
    for (int kt = 0; kt < 8; ++kt) {
        int cb = kt & 1;
        __syncthreads();
        if (kt < 7) STAGE(cb ^ 1, (kt + 1) * 32);
        const ushort_t* Ac = smem + (cb << 12);
        const ushort_t* Bc = smem + 8192 + (cb << 13);
        bf16x8 af[2];
#pragma unroll
        for (int i = 0; i < 2; ++i)
            af[i] = *(const bf16x8*)&Ac[(wm * 32 + i * 16 + r) * 32 + quad * 8];
#pragma unroll
        for (int j = 0; j < 8; ++j) {
            bf16x8 bfr = *(const bf16x8*)&Bc[(wn * 128 + j * 16 + r) * 32 + quad * 8];
            acc[0][j] = __builtin_amdgcn_mfma_f32_16x16x32_bf16(af[0], bfr, acc[0][j], 0, 0, 0);
            acc[1][j] = __builtin_amdgcn_mfma_f32_16x16x32_bf16(af[1], bfr, acc[1][j], 0, 0, 0);
        }
    }
#pragma unroll
    for (int i = 0; i < 2; ++i)
#pragma unroll
        for (int j = 0; j < 8; ++j) {
            int c = nBase + wn * 128 + j * 16 + r;
#pragma unroll
            for (int reg = 0; reg < 4; ++reg) {
                int m = mBase + wm * 32 + i * 16 + quad * 4 + reg;
                Y[(size_t)m * 512 + c] = f2bf(acc[i][j][reg]);
            }
        }
}

// ---------------- K4: scatter (via precomputed ranks) + GEMM layer 0 ----------------
__global__ __launch_bounds__(512) void scatgemm_kernel(
        const int* __restrict__ ei, const float* __restrict__ ew,
        const uint2* __restrict__ obnd, const ushort_t* __restrict__ rank16,
        uint2* __restrict__ es, int E,
        const ushort_t* __restrict__ xb, const ushort_t* __restrict__ wall,
        ushort_t* __restrict__ Yall) {
    __shared__ __align__(16) ushort_t smem[24576];
    int bx = blockIdx.x;
    if (bx < 200) {
        gemm_body(bx, xb, wall, Yall, smem);
        return;
    }
    int e = (bx - 200) * 512 + threadIdx.x;
    if (e < E) {
        int src = ei[e];
        int dst = ei[E + e];
        float w = ew[e];
        uint_t rk = rank16[e];
        if (w > 0.0f)
            es[obnd[dst].x + rk] = make_uint2((uint_t)src, __float_as_uint(w));
        else if (w < 0.0f)
            es[obnd[dst].y + rk] = make_uint2((uint_t)src, __float_as_uint(-w));
    }
}

// ---------------- standalone GEMM kernel (layers 1,2) ----------------
__global__ __launch_bounds__(512) void gemm_kernel(const ushort_t* __restrict__ A,
                                                   const ushort_t* __restrict__ Bw,
                                                   ushort_t* __restrict__ Y) {
    __shared__ __align__(16) ushort_t smem[24576];
    gemm_body(blockIdx.x, A, Bw, Y, smem);
}

// ---------------- aggregate projected rows + combine; DOT variant fuses readout ----------------
template <bool LEAKY, bool DOT>
__global__ __launch_bounds__(256) void agg_kernel(
        const ushort_t* __restrict__ Y,      // [12800 x 512]: Yp | Yn | Zp | Zn
        const uint2* __restrict__ obnd,
        const uint2* __restrict__ es,
        const float* __restrict__ bp, const float* __restrict__ bn,
        ushort_t* __restrict__ outp,         // !DOT: [12800 x 256]
        const float* __restrict__ weff,      // DOT: [51200]
        float* __restrict__ outg) {          // DOT: [64] (bias-initialized)
    int lane = threadIdx.x & 63;
    int wv   = threadIdx.x >> 6;
    int n = blockIdx.x * 4 + wv;
    int c0 = lane * 2;                       // 2 cols per lane, 0..127
    uint2 ob = obnd[n];
    uint_t off = ob.x, mid = ob.y, end = obnd[n + 1].x;

    float accp[2] = {0.f, 0.f};
    float accn[2] = {0.f, 0.f};

#pragma unroll 1
    for (int phase = 0; phase < 2; ++phase) {
        uint_t lo = phase ? mid : off;
        uint_t hi = phase ? end : mid;
        float* acc = phase ? accn : accp;
        const ushort_t* Yb = Y + (phase ? 128 : 0) + c0;
#pragma unroll 1
        for (uint_t base = lo; base < hi; base += 64) {
            int cnt = (int)min(64u, hi - base);
            uint2 rec = es[base + (uint_t)min(lane, cnt - 1)];
            int i = 0;
#pragma unroll 1
            for (; i + 8 <= cnt; i += 8) {
                int s[8]; float w[8]; uint_t u[8];
#pragma unroll
                for (int j = 0; j < 8; ++j) {
                    s[j] = __shfl((int)rec.x, i + j);
                    w[j] = __uint_as_float((uint_t)__shfl((int)rec.y, i + j));
                }
#pragma unroll
                for (int j = 0; j < 8; ++j) u[j] = *(const uint_t*)&Yb[(size_t)s[j] * 512];
#pragma unroll
                for (int j = 0; j < 8; ++j) {
                    acc[0] = fmaf(w[j], bf2f((ushort_t)(u[j] & 0xffffu)), acc[0]);
                    acc[1] = fmaf(w[j], bf2f((ushort_t)(u[j] >> 16)), acc[1]);
                }
            }
#pragma unroll 1
            for (; i < cnt; ++i) {
                int s = __shfl((int)rec.x, i);
                float w = __uint_as_float((uint_t)__shfl((int)rec.y, i));
                uint_t u = *(const uint_t*)&Yb[(size_t)s * 512];
                acc[0] = fmaf(w, bf2f((ushort_t)(u & 0xffffu)), acc[0]);
                acc[1] = fmaf(w, bf2f((ushort_t)(u >> 16)), acc[1]);
            }
        }
    }

    float dp = fmaxf((float)(mid - off), 1.0f);
    float dn = fmaxf((float)(end - mid), 1.0f);
    float rp = 1.0f / dp, rn = 1.0f / dn;
    uint_t zp = *(const uint_t*)&Y[(size_t)n * 512 + 256 + c0];
    uint_t zn = *(const uint_t*)&Y[(size_t)n * 512 + 384 + c0];
    float vp0 = fmaf(accp[0], rp, bf2f((ushort_t)(zp & 0xffffu)) + bp[c0]);
    float vp1 = fmaf(accp[1], rp, bf2f((ushort_t)(zp >> 16))     + bp[c0 + 1]);
    float vn0 = fmaf(accn[0], rn, bf2f((ushort_t)(zn & 0xffffu)) + bn[c0]);
    float vn1 = fmaf(accn[1], rn, bf2f((ushort_t)(zn >> 16))     + bn[c0 + 1]);
    if (LEAKY) {
        vp0 = (vp0 > 0.0f) ? vp0 : 0.01f * vp0;
        vp1 = (vp1 > 0.0f) ? vp1 : 0.01f * vp1;
        vn0 = (vn0 > 0.0f) ? vn0 : 0.01f * vn0;
        vn1 = (vn1 > 0.0f) ? vn1 : 0.01f * vn1;
    }
    if (DOT) {
        int g = n / 200;
        int kbase = (n - g * 200) * 256;
        float s = vp0 * weff[kbase + c0] + vp1 * weff[kbase + c0 + 1]
                + vn0 * weff[kbase + 128 + c0] + vn1 * weff[kbase + 128 + c0 + 1];
#pragma unroll
        for (int d = 32; d > 0; d >>= 1) s += __shfl_xor(s, d);
        if (lane == 0) atomicAdd(&outg[g], s);
    } else {
        uint_t op = (uint_t)f2bf(vp0) | ((uint_t)f2bf(vp1) << 16);
        uint_t on = (uint_t)f2bf(vn0) | ((uint_t)f2bf(vn1) << 16);
        *(uint_t*)&outp[(size_t)n * 256 + c0]       = op;
        *(uint_t*)&outp[(size_t)n * 256 + 128 + c0] = on;
    }
}

// ---------------- launch ----------------
extern "C" void kernel_launch(void* const* d_in, const int* in_sizes, int n_in,
                              void* d_out, int out_size, void* d_ws, size_t ws_size,
                              hipStream_t stream) {
    const float* x  = (const float*)d_in[0];
    const int*   ei = (const int*)d_in[1];
    const float* ew = (const float*)d_in[2];
    const float* Wp0 = (const float*)d_in[4];
    const float* bp0 = (const float*)d_in[5];
    const float* Wn0 = (const float*)d_in[6];
    const float* bn0 = (const float*)d_in[7];
    const float* Wp1 = (const float*)d_in[8];
    const float* bp1 = (const float*)d_in[9];
    const float* Wn1 = (const float*)d_in[10];
    const float* bn1 = (const float*)d_in[11];
    const float* Wp2 = (const float*)d_in[12];
    const float* bp2 = (const float*)d_in[13];
    const float* Wn2 = (const float*)d_in[14];
    const float* bn2 = (const float*)d_in[15];
    const float* Wr  = (const float*)d_in[16];
    const float* br  = (const float*)d_in[17];
    const float* Wl  = (const float*)d_in[18];
    const float* bl  = (const float*)d_in[19];
    const int E = in_sizes[1] / 2;   // 409600

    char* ws = (char*)d_ws;
    uint_t*   cnt    = (uint_t*)(ws + OFF_CNT);
    float*    weff   = (float*)(ws + OFF_WEFF);
    uint2*    obnd   = (uint2*)(ws + OFF_OBND);
    ushort_t* rank16 = (ushort_t*)(ws + OFF_RANK);
    uint2*    es     = (uint2*)(ws + OFF_ES);
    ushort_t* Yall   = (ushort_t*)(ws + OFF_YALL);
    ushort_t* hA     = (ushort_t*)(ws + OFF_HA);
    ushort_t* hB     = (ushort_t*)(ws + OFF_HB);
    ushort_t* wall   = (ushort_t*)(ws + OFF_WALL);
    ushort_t* xb     = (ushort_t*)(ws + OFF_XB);
    float*    outg   = (float*)d_out;

    // K1: zero cnt + wall cast + xb cast + weff
    hipLaunchKernelGGL(prep_kernel, dim3(512), dim3(256), 0, stream,
                       Wp0, Wn0, Wp1, Wn1, Wp2, Wn2, x, Wr, Wl, cnt, wall, xb, weff);
    // K2: histogram + ranks
    hipLaunchKernelGGL(hist_kernel, dim3((E + 511) / 512), dim3(512), 0, stream,
                       ei, ew, cnt, rank16, E);
    // K3: scan -> obnd; bias-init outg
    hipLaunchKernelGGL(scan_kernel, dim3(1), dim3(1024), 0, stream,
                       cnt, obnd, br, Wl, bl, outg, N_NODES);
    // K4: scatter + GEMM layer 0
    hipLaunchKernelGGL(scatgemm_kernel, dim3(200 + (E + 511) / 512), dim3(512), 0, stream,
                       ei, ew, obnd, rank16, es, E, xb, wall, Yall);
    // layer 0 agg
    hipLaunchKernelGGL((agg_kernel<true, false>), dim3(N_NODES / 4), dim3(256), 0, stream,
                       Yall, obnd, es, bp0, bn0, hA, (const float*)nullptr, (float*)nullptr);
    // layer 1
    hipLaunchKernelGGL(gemm_kernel, dim3(200), dim3(512), 0, stream, hA, wall + 131072, Yall);
    hipLaunchKernelGGL((agg_kernel<true, false>), dim3(N_NODES / 4), dim3(256), 0, stream,
                       Yall, obnd, es, bp1, bn1, hB, (const float*)nullptr, (float*)nullptr);
    // layer 2
    hipLaunchKernelGGL(gemm_kernel, dim3(200), dim3(512), 0, stream, hB, wall + 262144, Yall);
    hipLaunchKernelGGL((agg_kernel<false, true>), dim3(N_NODES / 4), dim3(256), 0, stream,
                       Yall, obnd, es, bp2, bn2, (ushort_t*)nullptr, weff, outg);
}

// Round 7
// 285.634 us; speedup vs baseline: 2.0477x; 1.2523x over previous
//
#include <hip/hip_runtime.h>

// ---------------- problem constants ----------------
#define NUM_GRAPHS 64
#define NODE_SZ    200
#define FEAT       200
#define HID        256
#define HALF       128
#define N_NODES    (NUM_GRAPHS * NODE_SZ)   // 12800
#define KREAD      (NODE_SZ * HID)          // 51200

typedef unsigned short ushort_t;
typedef unsigned int uint_t;
typedef __attribute__((ext_vector_type(8))) short bf16x8;
typedef __attribute__((ext_vector_type(4))) float f32x4;

#define GAS(p) ((const __attribute__((address_space(1))) void*)(p))
#define LAS(p) ((__attribute__((address_space(3))) void*)(p))

__device__ __forceinline__ float bf2f(ushort_t u) {
    union { unsigned int i; float f; } v; v.i = ((unsigned int)u) << 16; return v.f;
}
__device__ __forceinline__ ushort_t f2bf(float f) {
    union { float f; unsigned int i; } v; v.f = f;
    unsigned int x = v.i;
    unsigned int r = (x + 0x7fffu + ((x >> 16) & 1u)) >> 16;  // RNE
    return (ushort_t)r;
}

// ---------------- workspace offsets (bytes) ----------------
#define OFF_CNT    0              // 12800 u32 = 51,200
#define OFF_WEFF   51264          // 51200 f32 = 204,800
#define OFF_OBND   256064         // 12801 uint2 = 102,408
#define OFF_RANK   358472         // 409600 u16 = 819,200
#define OFF_ES     1177672        // 409600 uint2 = 3,276,800
#define OFF_YALL   4454480        // 12800*512*2 = 13,107,200
#define OFF_HA     17561680       // 6,553,600
#define OFF_HB     24115280       // 6,553,600
#define OFF_WALL   30668880       // 3*512*256*2 = 786,432
#define OFF_XB     31455312       // 6,553,600 -> 38,008,912

// ---------------- K1: wall cast + xb cast + weff + histogram(+rank16) ----------------
// (cnt zeroed by stream-ordered hipMemsetAsync before this kernel; all sections independent)
// Weight layout per layer (wall, [512 x 256] bf16):
//   rows 0..127: Wp[:, :K] | 128..255: Wn[:, :K] | 256..383: Wp[:, K:] | 384..511: Wn[:, K:]
// K=200 for layer 0 (cols 200..255 zero), K=256 for layers 1,2.
__global__ __launch_bounds__(256) void prep_kernel(
        const float* __restrict__ Wp0, const float* __restrict__ Wn0,
        const float* __restrict__ Wp1, const float* __restrict__ Wn1,
        const float* __restrict__ Wp2, const float* __restrict__ Wn2,
        const float* __restrict__ x, const float* __restrict__ Wr,
        const float* __restrict__ Wl,
        const int* __restrict__ ei, const float* __restrict__ ew, int E,
        uint_t* __restrict__ cnt, ushort_t* __restrict__ rank16,
        ushort_t* __restrict__ wall, ushort_t* __restrict__ xb,
        float* __restrict__ weff) {
    int gid = blockIdx.x * 256 + threadIdx.x;
    const int GS = gridDim.x * 256;                  // 131072
    for (int idx = gid; idx < 3 * 131072; idx += GS) {
        int layer = idx >> 17, within = idx & 131071;
        int rr = within >> 8, col = within & 255;
        const float* Wp = (layer == 0) ? Wp0 : (layer == 1) ? Wp1 : Wp2;
        const float* Wn = (layer == 0) ? Wn0 : (layer == 1) ? Wn1 : Wn2;
        int Ks = (layer == 0) ? 200 : 256;
        int q = rr >> 7;                             // 0:Pl 1:Nl 2:Pr 3:Nr
        const float* Wsrc = (q & 1) ? Wn : Wp;
        int row = rr & 127;
        int scol = col + ((q >> 1) ? Ks : 0);
        float v = (col < Ks) ? Wsrc[(size_t)row * (2 * Ks) + scol] : 0.0f;
        wall[idx] = f2bf(v);
    }
    for (int idx = gid; idx < N_NODES * 64; idx += GS) {
        int n = idx >> 6, c0 = (idx & 63) * 4;
        ushort4 o = {0, 0, 0, 0};
        if (c0 < 200) {
            float4 v = *(const float4*)&x[(size_t)n * 200 + c0];
            o.x = f2bf(v.x); o.y = f2bf(v.y); o.z = f2bf(v.z); o.w = f2bf(v.w);
        }
        *(ushort4*)&xb[(size_t)n * 256 + c0] = o;
    }
    // weff[k] = sum_c Wl[c] * Wr[c, k]   (ILP-8 over c)
    for (int k = gid; k < KREAD; k += GS) {
        float s[8] = {0.f, 0.f, 0.f, 0.f, 0.f, 0.f, 0.f, 0.f};
#pragma unroll 1
        for (int c = 0; c < 256; c += 8) {
#pragma unroll
            for (int j = 0; j < 8; ++j)
                s[j] = fmaf(Wl[c + j], Wr[(size_t)(c + j) * KREAD + k], s[j]);
        }
        weff[k] = ((s[0] + s[1]) + (s[2] + s[3])) + ((s[4] + s[5]) + (s[6] + s[7]));
    }
    // histogram + per-edge rank (atomic return value)
    for (int e = gid; e < E; e += GS) {
        int dst = ei[E + e];
        float w = ew[e];
        if (w > 0.0f) {
            uint_t old = atomicAdd(&cnt[dst], 1u);
            rank16[e] = (ushort_t)(old & 0xffffu);
        } else if (w < 0.0f) {
            uint_t old = atomicAdd(&cnt[dst], 0x10000u);
            rank16[e] = (ushort_t)(old >> 16);
        }
    }
}

// ---------------- K2: exclusive scan over packed counts -> obnd; bias-init outg ----------------
__global__ __launch_bounds__(1024) void scan_kernel(const uint_t* __restrict__ cnt,
                                                    uint2* __restrict__ obnd,
                                                    const float* __restrict__ br,
                                                    const float* __restrict__ Wl,
                                                    const float* __restrict__ bl,
                                                    float* __restrict__ outg, int n) {
    const int PER = 13;
    int t = threadIdx.x;
    int start = t * PER;
    int local[PER];
    uint_t pcnt[PER];
    int sum = 0;
#pragma unroll
    for (int i = 0; i < PER; ++i) {
        int idx = start + i;
        uint_t c = (idx < n) ? cnt[idx] : 0u;
        int v = (int)((c & 0xffffu) + (c >> 16));
        pcnt[i] = c & 0xffffu;
        local[i] = sum;
        sum += v;
    }
    int lane = t & 63, wid = t >> 6;
    int inc = sum;
#pragma unroll
    for (int d = 1; d < 64; d <<= 1) {
        int up = __shfl_up(inc, d);
        if (lane >= d) inc += up;
    }
    __shared__ int wsum[16], woff[16];
    if (lane == 63) wsum[wid] = inc;
    __syncthreads();
    if (t < 16) {
        int acc = 0;
        for (int j = 0; j < 16; ++j) if (j < t) acc += wsum[j];
        woff[t] = acc;
    }
    __syncthreads();
    int base = woff[wid] + (inc - sum);
#pragma unroll
    for (int i = 0; i < PER; ++i) {
        int idx = start + i;
        if (idx < n) {
            uint_t off = (uint_t)(base + local[i]);
            obnd[idx] = make_uint2(off, off + pcnt[i]);
        }
    }
    if (t == 1023) {
        uint_t tot = (uint_t)(base + sum);
        obnd[n] = make_uint2(tot, tot);
    }
    // bias-init: outg[g] = sum_c br[c]*Wl[c] + bl  (wave 0; butterfly gives all lanes the sum)
    if (t < 64) {
        float p = br[t] * Wl[t] + br[t + 64] * Wl[t + 64]
                + br[t + 128] * Wl[t + 128] + br[t + 192] * Wl[t + 192];
#pragma unroll
        for (int d = 32; d > 0; d >>= 1) p += __shfl_xor(p, d);
        outg[t] = p + bl[0];
    }
}

// ---------------- GEMM body: Y = A @ W^T, tile 128M x 256N, 8 waves, BK=32 ----------------
__device__ __forceinline__ void gemm_body(int t, const ushort_t* __restrict__ A,
                                          const ushort_t* __restrict__ Bw,
                                          ushort_t* __restrict__ Y,
                                          ushort_t* smem) {
    int mBase = (t >> 1) * 128;
    int nBase = (t & 1) * 256;
    int tid  = threadIdx.x;
    int lane = tid & 63;
    int wv   = tid >> 6;
    int r    = lane & 15;
    int quad = lane >> 4;
    int wm   = wv >> 1;        // 0..3 : M 32-block
    int wn   = wv & 1;         // 0..1 : N 128-block

    int rowA = tid >> 2, colc = (tid & 3) * 8;
    const ushort_t* gA  = A  + (size_t)(mBase + rowA) * 256 + colc;
    const ushort_t* gB0 = Bw + (size_t)(nBase + rowA) * 256 + colc;
    const ushort_t* gB1 = Bw + (size_t)(nBase + 128 + rowA) * 256 + colc;

    f32x4 acc[2][8];
#pragma unroll
    for (int i = 0; i < 2; ++i)
#pragma unroll
        for (int j = 0; j < 8; ++j) acc[i][j] = (f32x4){0.f, 0.f, 0.f, 0.f};

    auto STAGE = [&](int buf, int kb) {
        ushort_t* Ad = smem + (buf << 12) + tid * 8;
        ushort_t* Bd = smem + 8192 + (buf << 13) + tid * 8;
        __builtin_amdgcn_global_load_lds(GAS(gA + kb), LAS(Ad), 16, 0, 0);
        __builtin_amdgcn_global_load_lds(GAS(gB0 + kb), LAS(Bd), 16, 0, 0);
        __builtin_amdgcn_global_load_lds(GAS(gB1 + kb), LAS(Bd + 4096), 16, 0, 0);
    };

    STAGE(0, 0);
    for (int kt = 0; kt < 8; ++kt) {
        int cb = kt & 1;
        __syncthreads();
        if (kt < 7) STAGE(cb ^ 1, (kt + 1) * 32);
        const ushort_t* Ac = smem + (cb << 12);
        const ushort_t* Bc = smem + 8192 + (cb << 13);
        bf16x8 af[2];
#pragma unroll
        for (int i = 0; i < 2; ++i)
            af[i] = *(const bf16x8*)&Ac[(wm * 32 + i * 16 + r) * 32 + quad * 8];
#pragma unroll
        for (int j = 0; j < 8; ++j) {
            bf16x8 bfr = *(const bf16x8*)&Bc[(wn * 128 + j * 16 + r) * 32 + quad * 8];
            acc[0][j] = __builtin_amdgcn_mfma_f32_16x16x32_bf16(af[0], bfr, acc[0][j], 0, 0, 0);
            acc[1][j] = __builtin_amdgcn_mfma_f32_16x16x32_bf16(af[1], bfr, acc[1][j], 0, 0, 0);
        }
    }
#pragma unroll
    for (int i = 0; i < 2; ++i)
#pragma unroll
        for (int j = 0; j < 8; ++j) {
            int c = nBase + wn * 128 + j * 16 + r;
#pragma unroll
            for (int reg = 0; reg < 4; ++reg) {
                int m = mBase + wm * 32 + i * 16 + quad * 4 + reg;
                Y[(size_t)m * 512 + c] = f2bf(acc[i][j][reg]);
            }
        }
}

// ---------------- K3: scatter (via precomputed ranks) + GEMM layer 0 ----------------
__global__ __launch_bounds__(512) void scatgemm_kernel(
        const int* __restrict__ ei, const float* __restrict__ ew,
        const uint2* __restrict__ obnd, const ushort_t* __restrict__ rank16,
        uint2* __restrict__ es, int E,
        const ushort_t* __restrict__ xb, const ushort_t* __restrict__ wall,
        ushort_t* __restrict__ Yall) {
    __shared__ __align__(16) ushort_t smem[24576];
    int bx = blockIdx.x;
    if (bx < 200) {
        gemm_body(bx, xb, wall, Yall, smem);
        return;
    }
    int e = (bx - 200) * 512 + threadIdx.x;
    if (e < E) {
        int src = ei[e];
        int dst = ei[E + e];
        float w = ew[e];
        uint_t rk = rank16[e];
        if (w > 0.0f)
            es[obnd[dst].x + rk] = make_uint2((uint_t)src, __float_as_uint(w));
        else if (w < 0.0f)
            es[obnd[dst].y + rk] = make_uint2((uint_t)src, __float_as_uint(-w));
    }
}

// ---------------- standalone GEMM kernel (layers 1,2) ----------------
__global__ __launch_bounds__(512) void gemm_kernel(const ushort_t* __restrict__ A,
                                                   const ushort_t* __restrict__ Bw,
                                                   ushort_t* __restrict__ Y) {
    __shared__ __align__(16) ushort_t smem[24576];
    gemm_body(blockIdx.x, A, Bw, Y, smem);
}

// ---------------- aggregate projected rows + combine; DOT variant fuses readout ----------------
template <bool LEAKY, bool DOT>
__global__ __launch_bounds__(256) void agg_kernel(
        const ushort_t* __restrict__ Y,      // [12800 x 512]: Yp | Yn | Zp | Zn
        const uint2* __restrict__ obnd,
        const uint2* __restrict__ es,
        const float* __restrict__ bp, const float* __restrict__ bn,
        ushort_t* __restrict__ outp,         // !DOT: [12800 x 256]
        const float* __restrict__ weff,      // DOT: [51200]
        float* __restrict__ outg) {          // DOT: [64] (bias-initialized)
    __shared__ float sdot[4];
    int lane = threadIdx.x & 63;
    int wv   = threadIdx.x >> 6;
    int n = blockIdx.x * 4 + wv;
    int c0 = lane * 2;                       // 2 cols per lane, 0..127
    uint2 ob = obnd[n];
    uint_t off = ob.x, mid = ob.y, end = obnd[n + 1].x;

    float accp[2] = {0.f, 0.f};
    float accn[2] = {0.f, 0.f};

#pragma unroll 1
    for (int phase = 0; phase < 2; ++phase) {
        uint_t lo = phase ? mid : off;
        uint_t hi = phase ? end : mid;
        float* acc = phase ? accn : accp;
        const ushort_t* Yb = Y + (phase ? 128 : 0) + c0;
#pragma unroll 1
        for (uint_t base = lo; base < hi; base += 64) {
            int cnt = (int)min(64u, hi - base);
            uint2 rec = es[base + (uint_t)min(lane, cnt - 1)];
            int i = 0;
#pragma unroll 1
            for (; i + 8 <= cnt; i += 8) {
                int s[8]; float w[8]; uint_t u[8];
#pragma unroll
                for (int j = 0; j < 8; ++j) {
                    s[j] = __shfl((int)rec.x, i + j);
                    w[j] = __uint_as_float((uint_t)__shfl((int)rec.y, i + j));
                }
#pragma unroll
                for (int j = 0; j < 8; ++j) u[j] = *(const uint_t*)&Yb[(size_t)s[j] * 512];
#pragma unroll
                for (int j = 0; j < 8; ++j) {
                    acc[0] = fmaf(w[j], bf2f((ushort_t)(u[j] & 0xffffu)), acc[0]);
                    acc[1] = fmaf(w[j], bf2f((ushort_t)(u[j] >> 16)), acc[1]);
                }
            }
#pragma unroll 1
            for (; i < cnt; ++i) {
                int s = __shfl((int)rec.x, i);
                float w = __uint_as_float((uint_t)__shfl((int)rec.y, i));
                uint_t u = *(const uint_t*)&Yb[(size_t)s * 512];
                acc[0] = fmaf(w, bf2f((ushort_t)(u & 0xffffu)), acc[0]);
                acc[1] = fmaf(w, bf2f((ushort_t)(u >> 16)), acc[1]);
            }
        }
    }

    float dp = fmaxf((float)(mid - off), 1.0f);
    float dn = fmaxf((float)(end - mid), 1.0f);
    float rp = 1.0f / dp, rn = 1.0f / dn;
    uint_t zp = *(const uint_t*)&Y[(size_t)n * 512 + 256 + c0];
    uint_t zn = *(const uint_t*)&Y[(size_t)n * 512 + 384 + c0];
    float vp0 = fmaf(accp[0], rp, bf2f((ushort_t)(zp & 0xffffu)) + bp[c0]);
    float vp1 = fmaf(accp[1], rp, bf2f((ushort_t)(zp >> 16))     + bp[c0 + 1]);
    float vn0 = fmaf(accn[0], rn, bf2f((ushort_t)(zn & 0xffffu)) + bn[c0]);
    float vn1 = fmaf(accn[1], rn, bf2f((ushort_t)(zn >> 16))     + bn[c0 + 1]);
    if (LEAKY) {
        vp0 = (vp0 > 0.0f) ? vp0 : 0.01f * vp0;
        vp1 = (vp1 > 0.0f) ? vp1 : 0.01f * vp1;
        vn0 = (vn0 > 0.0f) ? vn0 : 0.01f * vn0;
        vn1 = (vn1 > 0.0f) ? vn1 : 0.01f * vn1;
    }
    if (DOT) {
        // block's 4 nodes share one graph (200 % 4 == 0): block-reduce, 1 atomic/block
        int g = blockIdx.x / 50;
        int kbase = (n % 200) * 256;
        float s = vp0 * weff[kbase + c0] + vp1 * weff[kbase + c0 + 1]
                + vn0 * weff[kbase + 128 + c0] + vn1 * weff[kbase + 128 + c0 + 1];
#pragma unroll
        for (int d = 32; d > 0; d >>= 1) s += __shfl_xor(s, d);
        if (lane == 0) sdot[wv] = s;
        __syncthreads();
        if (threadIdx.x == 0)
            atomicAdd(&outg[g], (sdot[0] + sdot[1]) + (sdot[2] + sdot[3]));
    } else {
        uint_t op = (uint_t)f2bf(vp0) | ((uint_t)f2bf(vp1) << 16);
        uint_t on = (uint_t)f2bf(vn0) | ((uint_t)f2bf(vn1) << 16);
        *(uint_t*)&outp[(size_t)n * 256 + c0]       = op;
        *(uint_t*)&outp[(size_t)n * 256 + 128 + c0] = on;
    }
}

// ---------------- launch ----------------
extern "C" void kernel_launch(void* const* d_in, const int* in_sizes, int n_in,
                              void* d_out, int out_size, void* d_ws, size_t ws_size,
                              hipStream_t stream) {
    const float* x  = (const float*)d_in[0];
    const int*   ei = (const int*)d_in[1];
    const float* ew = (const float*)d_in[2];
    const float* Wp0 = (const float*)d_in[4];
    const float* bp0 = (const float*)d_in[5];
    const float* Wn0 = (const float*)d_in[6];
    const float* bn0 = (const float*)d_in[7];
    const float* Wp1 = (const float*)d_in[8];
    const float* bp1 = (const float*)d_in[9];
    const float* Wn1 = (const float*)d_in[10];
    const float* bn1 = (const float*)d_in[11];
    const float* Wp2 = (const float*)d_in[12];
    const float* bp2 = (const float*)d_in[13];
    const float* Wn2 = (const float*)d_in[14];
    const float* bn2 = (const float*)d_in[15];
    const float* Wr  = (const float*)d_in[16];
    const float* br  = (const float*)d_in[17];
    const float* Wl  = (const float*)d_in[18];
    const float* bl  = (const float*)d_in[19];
    const int E = in_sizes[1] / 2;   // 409600

    char* ws = (char*)d_ws;
    uint_t*   cnt    = (uint_t*)(ws + OFF_CNT);
    float*    weff   = (float*)(ws + OFF_WEFF);
    uint2*    obnd   = (uint2*)(ws + OFF_OBND);
    ushort_t* rank16 = (ushort_t*)(ws + OFF_RANK);
    uint2*    es     = (uint2*)(ws + OFF_ES);
    ushort_t* Yall   = (ushort_t*)(ws + OFF_YALL);
    ushort_t* hA     = (ushort_t*)(ws + OFF_HA);
    ushort_t* hB     = (ushort_t*)(ws + OFF_HB);
    ushort_t* wall   = (ushort_t*)(ws + OFF_WALL);
    ushort_t* xb     = (ushort_t*)(ws + OFF_XB);
    float*    outg   = (float*)d_out;

    // zero the degree counters (stream-ordered; completes before prep)
    hipMemsetAsync(ws + OFF_CNT, 0, N_NODES * sizeof(uint_t), stream);
    // K1: wall cast + xb cast + weff + histogram(+rank16)
    hipLaunchKernelGGL(prep_kernel, dim3(512), dim3(256), 0, stream,
                       Wp0, Wn0, Wp1, Wn1, Wp2, Wn2, x, Wr, Wl,
                       ei, ew, E, cnt, rank16, wall, xb, weff);
    // K2: scan -> obnd; bias-init outg
    hipLaunchKernelGGL(scan_kernel, dim3(1), dim3(1024), 0, stream,
                       cnt, obnd, br, Wl, bl, outg, N_NODES);
    // K3: scatter + GEMM layer 0
    hipLaunchKernelGGL(scatgemm_kernel, dim3(200 + (E + 511) / 512), dim3(512), 0, stream,
                       ei, ew, obnd, rank16, es, E, xb, wall, Yall);
    // layer 0 agg
    hipLaunchKernelGGL((agg_kernel<true, false>), dim3(N_NODES / 4), dim3(256), 0, stream,
                       Yall, obnd, es, bp0, bn0, hA, (const float*)nullptr, (float*)nullptr);
    // layer 1
    hipLaunchKernelGGL(gemm_kernel, dim3(200), dim3(512), 0, stream, hA, wall + 131072, Yall);
    hipLaunchKernelGGL((agg_kernel<true, false>), dim3(N_NODES / 4), dim3(256), 0, stream,
                       Yall, obnd, es, bp1, bn1, hB, (const float*)nullptr, (float*)nullptr);
    // layer 2
    hipLaunchKernelGGL(gemm_kernel, dim3(200), dim3(512), 0, stream, hB, wall + 262144, Yall);
    hipLaunchKernelGGL((agg_kernel<false, true>), dim3(N_NODES / 4), dim3(256), 0, stream,
                       Yall, obnd, es, bp2, bn2, (ushort_t*)nullptr, weff, outg);
}

// Round 8
// 275.038 us; speedup vs baseline: 2.1266x; 1.0385x over previous
//
#include <hip/hip_runtime.h>

// ---------------- problem constants ----------------
#define NUM_GRAPHS 64
#define NODE_SZ    200
#define FEAT       200
#define HID        256
#define HALF       128
#define N_NODES    (NUM_GRAPHS * NODE_SZ)   // 12800
#define KREAD      (NODE_SZ * HID)          // 51200

typedef unsigned short ushort_t;
typedef unsigned int uint_t;
typedef __attribute__((ext_vector_type(8))) short bf16x8;
typedef __attribute__((ext_vector_type(4))) float f32x4;

#define GAS(p) ((const __attribute__((address_space(1))) void*)(p))
#define LAS(p) ((__attribute__((address_space(3))) void*)(p))

__device__ __forceinline__ float bf2f(ushort_t u) {
    union { unsigned int i; float f; } v; v.i = ((unsigned int)u) << 16; return v.f;
}
__device__ __forceinline__ ushort_t f2bf(float f) {
    union { float f; unsigned int i; } v; v.f = f;
    unsigned int x = v.i;
    unsigned int r = (x + 0x7fffu + ((x >> 16) & 1u)) >> 16;  // RNE
    return (ushort_t)r;
}

// ---------------- workspace offsets (bytes) ----------------
#define OFF_CNT    0              // 12800 u32 = 51,200
#define OFF_WEFF   51264          // 51200 f32 = 204,800
#define OFF_OBND   256064         // 12801 uint2 = 102,408
#define OFF_RANK   358472         // 409600 u16 = 819,200
#define OFF_ES     1177672        // 409600 uint2 = 3,276,800
#define OFF_YALL   4454480        // 12800*512*2 = 13,107,200
#define OFF_HA     17561680       // 6,553,600
#define OFF_HB     24115280       // 6,553,600
#define OFF_WALL   30668880       // 3*512*256*2 = 786,432
#define OFF_XB     31455312       // 6,553,600 -> 38,008,912

// ---------------- K1: block-partitioned prep ----------------
// blocks [0,200): weff | [200,300): xb cast | [300,364): wall cast | [364,516): hist+rank.
// (cnt zeroed by stream-ordered hipMemsetAsync before this kernel.)
// Weight layout per layer (wall, [512 x 256] bf16):
//   rows 0..127: Wp[:, :K] | 128..255: Wn[:, :K] | 256..383: Wp[:, K:] | 384..511: Wn[:, K:]
__global__ __launch_bounds__(256) void prep_kernel(
        const float* __restrict__ Wp0, const float* __restrict__ Wn0,
        const float* __restrict__ Wp1, const float* __restrict__ Wn1,
        const float* __restrict__ Wp2, const float* __restrict__ Wn2,
        const float* __restrict__ x, const float* __restrict__ Wr,
        const float* __restrict__ Wl,
        const int* __restrict__ ei, const float* __restrict__ ew, int E,
        uint_t* __restrict__ cnt, ushort_t* __restrict__ rank16,
        ushort_t* __restrict__ wall, ushort_t* __restrict__ xb,
        float* __restrict__ weff) {
    int bx = blockIdx.x, tid = threadIdx.x;
    if (bx < 200) {
        // weff[k] = sum_c Wl[c] * Wr[c, k]  -- ILP-16 over c
        int k = bx * 256 + tid;                      // < 51200
        float s[16];
#pragma unroll
        for (int j = 0; j < 16; ++j) s[j] = 0.f;
#pragma unroll 1
        for (int c = 0; c < 256; c += 16) {
#pragma unroll
            for (int j = 0; j < 16; ++j)
                s[j] = fmaf(Wl[c + j], Wr[(size_t)(c + j) * KREAD + k], s[j]);
        }
        float t0 = ((s[0] + s[1]) + (s[2] + s[3])) + ((s[4] + s[5]) + (s[6] + s[7]));
        float t1 = ((s[8] + s[9]) + (s[10] + s[11])) + ((s[12] + s[13]) + (s[14] + s[15]));
        weff[k] = t0 + t1;
    } else if (bx < 300) {
        for (int idx = (bx - 200) * 256 + tid; idx < N_NODES * 64; idx += 25600) {
            int n = idx >> 6, c0 = (idx & 63) * 4;
            ushort4 o = {0, 0, 0, 0};
            if (c0 < 200) {
                float4 v = *(const float4*)&x[(size_t)n * 200 + c0];
                o.x = f2bf(v.x); o.y = f2bf(v.y); o.z = f2bf(v.z); o.w = f2bf(v.w);
            }
            *(ushort4*)&xb[(size_t)n * 256 + c0] = o;
        }
    } else if (bx < 364) {
        for (int idx = (bx - 300) * 256 + tid; idx < 3 * 131072; idx += 16384) {
            int layer = idx >> 17, within = idx & 131071;
            int rr = within >> 8, col = within & 255;
            const float* Wp = (layer == 0) ? Wp0 : (layer == 1) ? Wp1 : Wp2;
            const float* Wn = (layer == 0) ? Wn0 : (layer == 1) ? Wn1 : Wn2;
            int Ks = (layer == 0) ? 200 : 256;
            int q = rr >> 7;                         // 0:Pl 1:Nl 2:Pr 3:Nr
            const float* Wsrc = (q & 1) ? Wn : Wp;
            int row = rr & 127;
            int scol = col + ((q >> 1) ? Ks : 0);
            float v = (col < Ks) ? Wsrc[(size_t)row * (2 * Ks) + scol] : 0.0f;
            wall[idx] = f2bf(v);
        }
    } else {
        for (int e = (bx - 364) * 256 + tid; e < E; e += 38912) {
            int dst = ei[E + e];
            float w = ew[e];
            if (w > 0.0f) {
                uint_t old = atomicAdd(&cnt[dst], 1u);
                rank16[e] = (ushort_t)(old & 0xffffu);
            } else if (w < 0.0f) {
                uint_t old = atomicAdd(&cnt[dst], 0x10000u);
                rank16[e] = (ushort_t)(old >> 16);
            }
        }
    }
}

// ---------------- K2: exclusive scan over packed counts -> obnd; bias-init outg ----------------
__global__ __launch_bounds__(1024) void scan_kernel(const uint_t* __restrict__ cnt,
                                                    uint2* __restrict__ obnd,
                                                    const float* __restrict__ br,
                                                    const float* __restrict__ Wl,
                                                    const float* __restrict__ bl,
                                                    float* __restrict__ outg, int n) {
    const int PER = 13;
    int t = threadIdx.x;
    int start = t * PER;
    int local[PER];
    uint_t pcnt[PER];
    int sum = 0;
#pragma unroll
    for (int i = 0; i < PER; ++i) {
        int idx = start + i;
        uint_t c = (idx < n) ? cnt[idx] : 0u;
        int v = (int)((c & 0xffffu) + (c >> 16));
        pcnt[i] = c & 0xffffu;
        local[i] = sum;
        sum += v;
    }
    int lane = t & 63, wid = t >> 6;
    int inc = sum;
#pragma unroll
    for (int d = 1; d < 64; d <<= 1) {
        int up = __shfl_up(inc, d);
        if (lane >= d) inc += up;
    }
    __shared__ int wsum[16], woff[16];
    if (lane == 63) wsum[wid] = inc;
    __syncthreads();
    if (t < 16) {
        int acc = 0;
        for (int j = 0; j < 16; ++j) if (j < t) acc += wsum[j];
        woff[t] = acc;
    }
    __syncthreads();
    int base = woff[wid] + (inc - sum);
#pragma unroll
    for (int i = 0; i < PER; ++i) {
        int idx = start + i;
        if (idx < n) {
            uint_t off = (uint_t)(base + local[i]);
            obnd[idx] = make_uint2(off, off + pcnt[i]);
        }
    }
    if (t == 1023) {
        uint_t tot = (uint_t)(base + sum);
        obnd[n] = make_uint2(tot, tot);
    }
    // bias-init: outg[g] = sum_c br[c]*Wl[c] + bl
    if (t < 64) {
        float p = br[t] * Wl[t] + br[t + 64] * Wl[t + 64]
                + br[t + 128] * Wl[t + 128] + br[t + 192] * Wl[t + 192];
#pragma unroll
        for (int d = 32; d > 0; d >>= 1) p += __shfl_xor(p, d);
        outg[t] = p + bl[0];
    }
}

// ---------------- GEMM body: Y = A @ W^T, tile 128M x 256N, 8 waves, BK=32 ----------------
__device__ __forceinline__ void gemm_body(int t, const ushort_t* __restrict__ A,
                                          const ushort_t* __restrict__ Bw,
                                          ushort_t* __restrict__ Y,
                                          ushort_t* smem) {
    int mBase = (t >> 1) * 128;
    int nBase = (t & 1) * 256;
    int tid  = threadIdx.x;
    int lane = tid & 63;
    int wv   = tid >> 6;
    int r    = lane & 15;
    int quad = lane >> 4;
    int wm   = wv >> 1;        // 0..3 : M 32-block
    int wn   = wv & 1;         // 0..1 : N 128-block

    int rowA = tid >> 2, colc = (tid & 3) * 8;
    const ushort_t* gA  = A  + (size_t)(mBase + rowA) * 256 + colc;
    const ushort_t* gB0 = Bw + (size_t)(nBase + rowA) * 256 + colc;
    const ushort_t* gB1 = Bw + (size_t)(nBase + 128 + rowA) * 256 + colc;

    f32x4 acc[2][8];
#pragma unroll
    for (int i = 0; i < 2; ++i)
#pragma unroll
        for (int j = 0; j < 8; ++j) acc[i][j] = (f32x4){0.f, 0.f, 0.f, 0.f};

    auto STAGE = [&](int buf, int kb) {
        ushort_t* Ad = smem + (buf << 12) + tid * 8;
        ushort_t* Bd = smem + 8192 + (buf << 13) + tid * 8;
        __builtin_amdgcn_global_load_lds(GAS(gA + kb), LAS(Ad), 16, 0, 0);
        __builtin_amdgcn_global_load_lds(GAS(gB0 + kb), LAS(Bd), 16, 0, 0);
        __builtin_amdgcn_global_load_lds(GAS(gB1 + kb), LAS(Bd + 4096), 16, 0, 0);
    };

    STAGE(0, 0);
    for (int kt = 0; kt < 8; ++kt) {
        int cb = kt & 1;
        __syncthreads();
        if (kt < 7) STAGE(cb ^ 1, (kt + 1) * 32);
        const ushort_t* Ac = smem + (cb << 12);
        const ushort_t* Bc = smem + 8192 + (cb << 13);
        bf16x8 af[2];
#pragma unroll
        for (int i = 0; i < 2; ++i)
            af[i] = *(const bf16x8*)&Ac[(wm * 32 + i * 16 + r) * 32 + quad * 8];
#pragma unroll
        for (int j = 0; j < 8; ++j) {
            bf16x8 bfr = *(const bf16x8*)&Bc[(wn * 128 + j * 16 + r) * 32 + quad * 8];
            acc[0][j] = __builtin_amdgcn_mfma_f32_16x16x32_bf16(af[0], bfr, acc[0][j], 0, 0, 0);
            acc[1][j] = __builtin_amdgcn_mfma_f32_16x16x32_bf16(af[1], bfr, acc[1][j], 0, 0, 0);
        }
    }
#pragma unroll
    for (int i = 0; i < 2; ++i)
#pragma unroll
        for (int j = 0; j < 8; ++j) {
            int c = nBase + wn * 128 + j * 16 + r;
#pragma unroll
            for (int reg = 0; reg < 4; ++reg) {
                int m = mBase + wm * 32 + i * 16 + quad * 4 + reg;
                Y[(size_t)m * 512 + c] = f2bf(acc[i][j][reg]);
            }
        }
}

// ---------------- K3: scatter (via precomputed ranks) + GEMM layer 0 ----------------
__global__ __launch_bounds__(512) void scatgemm_kernel(
        const int* __restrict__ ei, const float* __restrict__ ew,
        const uint2* __restrict__ obnd, const ushort_t* __restrict__ rank16,
        uint2* __restrict__ es, int E,
        const ushort_t* __restrict__ xb, const ushort_t* __restrict__ wall,
        ushort_t* __restrict__ Yall) {
    __shared__ __align__(16) ushort_t smem[24576];
    int bx = blockIdx.x;
    if (bx < 200) {
        gemm_body(bx, xb, wall, Yall, smem);
        return;
    }
    int e = (bx - 200) * 512 + threadIdx.x;
    if (e < E) {
        int src = ei[e];
        int dst = ei[E + e];
        float w = ew[e];
        uint_t rk = rank16[e];
        if (w > 0.0f)
            es[obnd[dst].x + rk] = make_uint2((uint_t)src, __float_as_uint(w));
        else if (w < 0.0f)
            es[obnd[dst].y + rk] = make_uint2((uint_t)src, __float_as_uint(-w));
    }
}

// ---------------- standalone GEMM kernel (layers 1,2) ----------------
__global__ __launch_bounds__(512) void gemm_kernel(const ushort_t* __restrict__ A,
                                                   const ushort_t* __restrict__ Bw,
                                                   ushort_t* __restrict__ Y) {
    __shared__ __align__(16) ushort_t smem[24576];
    gemm_body(blockIdx.x, A, Bw, Y, smem);
}

// ---------------- gather batch: scalar edge records + saddr row gathers ----------------
// e, hi wave-uniform; es records land in SGPRs; per gather = SALU addr + load + 2 FMA.
template <int B, bool CLAMP>
__device__ __forceinline__ void gather_batch(const uint2* __restrict__ es,
                                             uint_t e, uint_t hi,
                                             const ushort_t* __restrict__ Yph, int c0,
                                             float* __restrict__ acc) {
    uint_t u[B];
    float  w[B];
#pragma unroll
    for (int j = 0; j < B; ++j) {
        uint_t idx = CLAMP ? min(e + (uint_t)j, hi - 1u) : (e + (uint_t)j);
        uint2 r = es[idx];
        uint_t s = __builtin_amdgcn_readfirstlane(r.x);
        float  wj = __uint_as_float(r.y);
        w[j] = (CLAMP && (e + (uint_t)j >= hi)) ? 0.0f : wj;
        const ushort_t* rowp = Yph + (size_t)s * 512;
        u[j] = *(const uint_t*)&rowp[c0];
    }
#pragma unroll
    for (int j = 0; j < B; ++j) {
        acc[0] = fmaf(w[j], bf2f((ushort_t)(u[j] & 0xffffu)), acc[0]);
        acc[1] = fmaf(w[j], bf2f((ushort_t)(u[j] >> 16)), acc[1]);
    }
}

// ---------------- aggregate projected rows + combine; DOT variant fuses readout ----------------
template <bool LEAKY, bool DOT>
__global__ __launch_bounds__(256) void agg_kernel(
        const ushort_t* __restrict__ Y,      // [12800 x 512]: Yp | Yn | Zp | Zn
        const uint2* __restrict__ obnd,
        const uint2* __restrict__ es,
        const float* __restrict__ bp, const float* __restrict__ bn,
        ushort_t* __restrict__ outp,         // !DOT: [12800 x 256]
        const float* __restrict__ weff,      // DOT: [51200]
        float* __restrict__ outg) {          // DOT: [64] (bias-initialized)
    __shared__ float sdot[4];
    int lane = threadIdx.x & 63;
    int wv   = threadIdx.x >> 6;
    int n = blockIdx.x * 4 + wv;
    int c0 = lane * 2;                       // 2 cols per lane, 0..127
    uint2 ob = obnd[n];
    uint_t off = __builtin_amdgcn_readfirstlane(ob.x);
    uint_t mid = __builtin_amdgcn_readfirstlane(ob.y);
    uint_t end = __builtin_amdgcn_readfirstlane(obnd[n + 1].x);

    float accp[2] = {0.f, 0.f};
    float accn[2] = {0.f, 0.f};

#pragma unroll 1
    for (int phase = 0; phase < 2; ++phase) {
        uint_t e  = phase ? mid : off;
        uint_t hi = phase ? end : mid;
        float* acc = phase ? accn : accp;
        const ushort_t* Yph = Y + (phase ? 128 : 0);
#pragma unroll 1
        while (e + 16 <= hi) { gather_batch<16, false>(es, e, hi, Yph, c0, acc); e += 16; }
        if (e + 8 <= hi)     { gather_batch<8,  false>(es, e, hi, Yph, c0, acc); e += 8; }
        if (e < hi)          { gather_batch<8,  true >(es, e, hi, Yph, c0, acc); }
    }

    float dp = fmaxf((float)(mid - off), 1.0f);
    float dn = fmaxf((float)(end - mid), 1.0f);
    float rp = 1.0f / dp, rn = 1.0f / dn;
    uint_t zp = *(const uint_t*)&Y[(size_t)n * 512 + 256 + c0];
    uint_t zn = *(const uint_t*)&Y[(size_t)n * 512 + 384 + c0];
    float vp0 = fmaf(accp[0], rp, bf2f((ushort_t)(zp & 0xffffu)) + bp[c0]);
    float vp1 = fmaf(accp[1], rp, bf2f((ushort_t)(zp >> 16))     + bp[c0 + 1]);
    float vn0 = fmaf(accn[0], rn, bf2f((ushort_t)(zn & 0xffffu)) + bn[c0]);
    float vn1 = fmaf(accn[1], rn, bf2f((ushort_t)(zn >> 16))     + bn[c0 + 1]);
    if (LEAKY) {
        vp0 = (vp0 > 0.0f) ? vp0 : 0.01f * vp0;
        vp1 = (vp1 > 0.0f) ? vp1 : 0.01f * vp1;
        vn0 = (vn0 > 0.0f) ? vn0 : 0.01f * vn0;
        vn1 = (vn1 > 0.0f) ? vn1 : 0.01f * vn1;
    }
    if (DOT) {
        // block's 4 nodes share one graph (200 % 4 == 0): block-reduce, 1 atomic/block
        int g = blockIdx.x / 50;
        int kbase = (n % 200) * 256;
        float s = vp0 * weff[kbase + c0] + vp1 * weff[kbase + c0 + 1]
                + vn0 * weff[kbase + 128 + c0] + vn1 * weff[kbase + 128 + c0 + 1];
#pragma unroll
        for (int d = 32; d > 0; d >>= 1) s += __shfl_xor(s, d);
        if (lane == 0) sdot[wv] = s;
        __syncthreads();
        if (threadIdx.x == 0)
            atomicAdd(&outg[g], (sdot[0] + sdot[1]) + (sdot[2] + sdot[3]));
    } else {
        uint_t op = (uint_t)f2bf(vp0) | ((uint_t)f2bf(vp1) << 16);
        uint_t on = (uint_t)f2bf(vn0) | ((uint_t)f2bf(vn1) << 16);
        *(uint_t*)&outp[(size_t)n * 256 + c0]       = op;
        *(uint_t*)&outp[(size_t)n * 256 + 128 + c0] = on;
    }
}

// ---------------- launch ----------------
extern "C" void kernel_launch(void* const* d_in, const int* in_sizes, int n_in,
                              void* d_out, int out_size, void* d_ws, size_t ws_size,
                              hipStream_t stream) {
    const float* x  = (const float*)d_in[0];
    const int*   ei = (const int*)d_in[1];
    const float* ew = (const float*)d_in[2];
    const float* Wp0 = (const float*)d_in[4];
    const float* bp0 = (const float*)d_in[5];
    const float* Wn0 = (const float*)d_in[6];
    const float* bn0 = (const float*)d_in[7];
    const float* Wp1 = (const float*)d_in[8];
    const float* bp1 = (const float*)d_in[9];
    const float* Wn1 = (const float*)d_in[10];
    const float* bn1 = (const float*)d_in[11];
    const float* Wp2 = (const float*)d_in[12];
    const float* bp2 = (const float*)d_in[13];
    const float* Wn2 = (const float*)d_in[14];
    const float* bn2 = (const float*)d_in[15];
    const float* Wr  = (const float*)d_in[16];
    const float* br  = (const float*)d_in[17];
    const float* Wl  = (const float*)d_in[18];
    const float* bl  = (const float*)d_in[19];
    const int E = in_sizes[1] / 2;   // 409600

    char* ws = (char*)d_ws;
    uint_t*   cnt    = (uint_t*)(ws + OFF_CNT);
    float*    weff   = (float*)(ws + OFF_WEFF);
    uint2*    obnd   = (uint2*)(ws + OFF_OBND);
    ushort_t* rank16 = (ushort_t*)(ws + OFF_RANK);
    uint2*    es     = (uint2*)(ws + OFF_ES);
    ushort_t* Yall   = (ushort_t*)(ws + OFF_YALL);
    ushort_t* hA     = (ushort_t*)(ws + OFF_HA);
    ushort_t* hB     = (ushort_t*)(ws + OFF_HB);
    ushort_t* wall   = (ushort_t*)(ws + OFF_WALL);
    ushort_t* xb     = (ushort_t*)(ws + OFF_XB);
    float*    outg   = (float*)d_out;

    // zero the degree counters (stream-ordered; completes before prep)
    hipMemsetAsync(ws + OFF_CNT, 0, N_NODES * sizeof(uint_t), stream);
    // K1: block-partitioned prep (weff | xb | wall | hist)
    hipLaunchKernelGGL(prep_kernel, dim3(516), dim3(256), 0, stream,
                       Wp0, Wn0, Wp1, Wn1, Wp2, Wn2, x, Wr, Wl,
                       ei, ew, E, cnt, rank16, wall, xb, weff);
    // K2: scan -> obnd; bias-init outg
    hipLaunchKernelGGL(scan_kernel, dim3(1), dim3(1024), 0, stream,
                       cnt, obnd, br, Wl, bl, outg, N_NODES);
    // K3: scatter + GEMM layer 0
    hipLaunchKernelGGL(scatgemm_kernel, dim3(200 + (E + 511) / 512), dim3(512), 0, stream,
                       ei, ew, obnd, rank16, es, E, xb, wall, Yall);
    // layer 0 agg
    hipLaunchKernelGGL((agg_kernel<true, false>), dim3(N_NODES / 4), dim3(256), 0, stream,
                       Yall, obnd, es, bp0, bn0, hA, (const float*)nullptr, (float*)nullptr);
    // layer 1
    hipLaunchKernelGGL(gemm_kernel, dim3(200), dim3(512), 0, stream, hA, wall + 131072, Yall);
    hipLaunchKernelGGL((agg_kernel<true, false>), dim3(N_NODES / 4), dim3(256), 0, stream,
                       Yall, obnd, es, bp1, bn1, hB, (const float*)nullptr, (float*)nullptr);
    // layer 2
    hipLaunchKernelGGL(gemm_kernel, dim3(200), dim3(512), 0, stream, hB, wall + 262144, Yall);
    hipLaunchKernelGGL((agg_kernel<false, true>), dim3(N_NODES / 4), dim3(256), 0, stream,
                       Yall, obnd, es, bp2, bn2, (ushort_t*)nullptr, weff, outg);
}